// Round 5
// baseline (4567.238 us; speedup 1.0000x reference)
//
#include <hip/hip_runtime.h>

// ---------------------------------------------------------------------------
// Two-layer tanh RNN — concurrent-layer persistent kernel, round 5.
// B=64, T=512, H=512, I=128, W_OUT=32. fp32 in/out, f16-pair internal, fp32 acc.
//
// Grid 512 WGs x 256 (launch_bounds(256,2), all co-resident). gid bits:
//   [2:0]=glo (XCD under rr dispatch), [4:3]=ghi, [5]=layer, [8:6]=wgr.
//   => all 16 WGs of batch-pair g = ghi*8+glo (both layers, 8 row-groups)
//   share one XCD: every exchange rides the local L2 fast path.
// Exchange: dual-address tagged atoms {tag<<32|f16pair}:
//   - local ring:  plain volatile store/load (XCD L2, fast, heuristic)
//   - agent ring:  relaxed agent-scope atomics (MALL, authoritative fallback)
// Phase-split: each lane's chunk = input-half + recurrent-half; input-half
// partial computed BEFORE the recurrent poll, so only 64 pairs of dot remain
// on the post->post critical cycle.
// Layer-0 throttled to <=12 steps ahead of layer-1 (h0 ring = 32 deep).
// ---------------------------------------------------------------------------

#define T_STEPS 512
#define NBATCH  64
#define D0RING  32
#define D1RING  4
#define LEAD    12

typedef _Float16 half2v __attribute__((ext_vector_type(2)));
typedef unsigned long long ull;

__device__ __forceinline__ unsigned pack2(float a, float b) {
    _Float16 fa = (_Float16)a, fb = (_Float16)b;
    unsigned short ua = __builtin_bit_cast(unsigned short, fa);
    unsigned short ub = __builtin_bit_cast(unsigned short, fb);
    return (unsigned)ua | ((unsigned)ub << 16);
}

__device__ __forceinline__ float dot2acc(unsigned w, unsigned h, float acc) {
#if __has_builtin(__builtin_amdgcn_fdot2)
    return __builtin_amdgcn_fdot2(__builtin_bit_cast(half2v, w),
                                  __builtin_bit_cast(half2v, h), acc, false);
#else
    half2v wv = __builtin_bit_cast(half2v, w);
    half2v hv = __builtin_bit_cast(half2v, h);
    acc = fmaf((float)wv.x, (float)hv.x, acc);
    return fmaf((float)wv.y, (float)hv.y, acc);
#endif
}

__device__ __forceinline__ float fast_tanh(float xv) {
    float e2 = __builtin_amdgcn_exp2f(xv * 2.885390082f);
    return 1.f - 2.f * __builtin_amdgcn_rcpf(e2 + 1.f);
}

__device__ __forceinline__ ull ld_plain(const ull* p) {
    return *(const volatile ull*)p;                     // sc0: local-XCD L2
}
__device__ __forceinline__ ull ld_agent(const ull* p) {
    return __hip_atomic_load(p, __ATOMIC_RELAXED, __HIP_MEMORY_SCOPE_AGENT);
}
__device__ __forceinline__ void post_dual(ull* pl, ull* pg, ull atom) {
    *(volatile ull*)pl = atom;                          // local L2 (fast hint)
    __hip_atomic_store(pg, atom, __ATOMIC_RELAXED, __HIP_MEMORY_SCOPE_AGENT);
}

// Poll two tagged words (one per batch of the pair); local first, agent fallback.
__device__ __forceinline__ void poll2(ull* pl0, ull* pg0, ull* pl1, ull* pg1,
                                      unsigned tag, unsigned& r0, unsigned& r1,
                                      long& budget) {
    bool d0 = false, d1 = false;
    for (;;) {
        if (!d0) { ull v = ld_plain(pl0); if ((unsigned)(v >> 32) == tag) { r0 = (unsigned)v; d0 = true; } }
        if (!d1) { ull v = ld_plain(pl1); if ((unsigned)(v >> 32) == tag) { r1 = (unsigned)v; d1 = true; } }
        if (d0 && d1) return;
        if (!d0) { ull v = ld_agent(pg0); if ((unsigned)(v >> 32) == tag) { r0 = (unsigned)v; d0 = true; } }
        if (!d1) { ull v = ld_agent(pg1); if ((unsigned)(v >> 32) == tag) { r1 = (unsigned)v; d1 = true; } }
        if (d0 && d1) return;
        if (--budget < 0) return;
    }
}

// Packed weights [wgr<8][j<P][lane<256]; phase-split k-mapping (see init_pack).
#define N0 (8 * 80 * 256)
#define N1 (8 * 128 * 256)

__global__ void init_pack(const float* __restrict__ Wih0, const float* __restrict__ Whh0,
                          const float* __restrict__ Wih1, const float* __restrict__ Whh1,
                          unsigned* __restrict__ wp0, unsigned* __restrict__ wp1) {
    int gid = blockIdx.x * 256 + threadIdx.x;
    if (gid < N0) {
        int L = gid & 255; int j = (gid >> 8) % 80; int wg = (gid >> 8) / 80;
        int r = wg * 64 + (L >> 2); int c = L & 3;
        float w0, w1;
        if (j < 16) { int k = c * 32 + 2 * j;          // x quarter (16 pairs)
            w0 = Wih0[r * 128 + k]; w1 = Wih0[r * 128 + k + 1];
        } else      { int k = c * 128 + 2 * (j - 16);  // h0 quarter (64 pairs)
            w0 = Whh0[r * 512 + k]; w1 = Whh0[r * 512 + k + 1]; }
        wp0[gid] = pack2(w0, w1);
    } else {
        int g2 = gid - N0;
        if (g2 < N1) {
            int L = g2 & 255; int j = (g2 >> 8) % 128; int wg = (g2 >> 8) / 128;
            int r = wg * 64 + (L >> 2); int c = L & 3;
            float w0, w1;
            if (j < 64) { int k = c * 128 + 2 * j;         // h0 quarter
                w0 = Wih1[r * 512 + k]; w1 = Wih1[r * 512 + k + 1];
            } else      { int k = c * 128 + 2 * (j - 64);  // h1 quarter
                w0 = Whh1[r * 512 + k]; w1 = Whh1[r * 512 + k + 1]; }
            wp1[g2] = pack2(w0, w1);
        }
    }
}

__global__ __launch_bounds__(256, 2)
void rnn_dual(const float* __restrict__ x, const float* __restrict__ noise,
              const unsigned* __restrict__ wp0, const unsigned* __restrict__ wp1,
              const float* __restrict__ bih0, const float* __restrict__ bhh0,
              const float* __restrict__ bih1, const float* __restrict__ bhh1,
              const float* __restrict__ fcw, const float* __restrict__ fcb,
              ull* __restrict__ h0l, ull* __restrict__ h0g,
              ull* __restrict__ h1l, ull* __restrict__ h1g,
              float* __restrict__ out) {
    const int L   = threadIdx.x;
    const int gid = blockIdx.x;
    const int glo = gid & 7, ghi = (gid >> 3) & 3;
    const int layer = (gid >> 5) & 1;
    const int wgr = gid >> 6;
    const int g = ghi * 8 + glo, b0 = 2 * g;
    const int c = L & 3, rloc = L >> 2, r = wgr * 64 + rloc;

    long budget = 20000000L;             // hang bailout only

    if (layer == 0) {
        unsigned wreg[80];
#pragma unroll
        for (int j = 0; j < 80; ++j) {
            wreg[j] = wp0[(wgr * 80 + j) * 256 + L];
            asm volatile("" : "+v"(wreg[j]));
        }
        const float cb = bih0[r] + bhh0[r];

        __shared__ __align__(16) unsigned xA[2][4][20];   // x(t): 16 pairs/chunk (+pad)
        __shared__ __align__(16) unsigned hR[2][4][68];   // h0(t-1): 64 pairs/chunk (+pad)
        for (int i = L; i < 2 * 4 * 68; i += 256) ((unsigned*)hR)[i] = 0u;  // h0(-1)=0
        if (L < 128) {                                    // x(0)
            int bb = L >> 6, i = L & 63;
            float2 xf = *(const float2*)(x + ((size_t)(b0 + bb) * T_STEPS) * 128 + 2 * i);
            xA[bb][i >> 4][i & 15] = pack2(xf.x, xf.y);
        }
        __syncthreads();
        float nz[2];
#pragma unroll
        for (int bb = 0; bb < 2; ++bb)
            nz[bb] = noise[(((size_t)(b0 + bb) * T_STEPS) * 2 + 0) * 512 + r];

        for (int t = 0; t < T_STEPS; ++t) {
            // phase-1: x-part partial (wreg[0..15])
            float p1[2];
#pragma unroll
            for (int bb = 0; bb < 2; ++bb) {
                const uint4* q = (const uint4*)(&xA[bb][c][0]);
                float a0 = 0.f, a1 = 0.f, a2 = 0.f, a3 = 0.f;
#pragma unroll
                for (int jj = 0; jj < 4; ++jj) {
                    uint4 hp = q[jj];
                    a0 = dot2acc(wreg[4 * jj + 0], hp.x, a0);
                    a1 = dot2acc(wreg[4 * jj + 1], hp.y, a1);
                    a2 = dot2acc(wreg[4 * jj + 2], hp.z, a2);
                    a3 = dot2acc(wreg[4 * jj + 3], hp.w, a3);
                }
                p1[bb] = (a0 + a1) + (a2 + a3);
            }
            // poll own h0(t-1): tag t, slot (t-1)&31
            if (t > 0) {
                size_t base = (size_t)((t - 1) & (D0RING - 1)) * NBATCH * 256;
                unsigned r0, r1;
                poll2(&h0l[base + (size_t)b0 * 256 + L], &h0g[base + (size_t)b0 * 256 + L],
                      &h0l[base + (size_t)(b0 + 1) * 256 + L], &h0g[base + (size_t)(b0 + 1) * 256 + L],
                      (unsigned)t, r0, r1, budget);
                hR[0][L >> 6][L & 63] = r0;
                hR[1][L >> 6][L & 63] = r1;
            }
            __syncthreads();
            // phase-2: recurrent part (wreg[16..79]) — the critical half
            float hnew[2];
#pragma unroll
            for (int bb = 0; bb < 2; ++bb) {
                const uint4* q = (const uint4*)(&hR[bb][c][0]);
                float a0 = 0.f, a1 = 0.f, a2 = 0.f, a3 = 0.f;
#pragma unroll
                for (int jj = 0; jj < 16; ++jj) {
                    uint4 hp = q[jj];
                    a0 = dot2acc(wreg[16 + 4 * jj + 0], hp.x, a0);
                    a1 = dot2acc(wreg[16 + 4 * jj + 1], hp.y, a1);
                    a2 = dot2acc(wreg[16 + 4 * jj + 2], hp.z, a2);
                    a3 = dot2acc(wreg[16 + 4 * jj + 3], hp.w, a3);
                }
                float acc = p1[bb] + (a0 + a1) + (a2 + a3);
                acc += __shfl_xor(acc, 1);
                acc += __shfl_xor(acc, 2);
                hnew[bb] = fast_tanh(acc + cb + nz[bb]);
            }
            // post h0(t): tag t+1, slot t&31 (dual address)
#pragma unroll
            for (int bb = 0; bb < 2; ++bb) {
                float hnb = __shfl_down(hnew[bb], 4);
                if ((L & 7) == 0) {
                    unsigned pv = pack2(hnew[bb], hnb);
                    ull atom = ((ull)(unsigned)(t + 1) << 32) | (ull)pv;
                    size_t idx = ((size_t)(t & (D0RING - 1)) * NBATCH + (b0 + bb)) * 256 + (r >> 1);
                    post_dual(&h0l[idx], &h0g[idx], atom);
                }
            }
            if (t == T_STEPS - 1) break;
            // throttle: stay <= LEAD steps ahead of layer-1
            if (t >= LEAD) {
                size_t idx = ((size_t)((t - LEAD) & (D1RING - 1)) * NBATCH + b0) * 256 + L;
                unsigned target = (unsigned)(t - LEAD + 1);
                for (;;) {
                    ull v = ld_plain(&h1l[idx]); unsigned tg = (unsigned)(v >> 32);
                    if (tg >= target && tg <= 1025u) break;
                    v = ld_agent(&h1g[idx]); tg = (unsigned)(v >> 32);
                    if (tg >= target && tg <= 1025u) break;
                    if (--budget < 0) break;
                }
            }
            // prefetch x(t+1), nz(t+1); scatter x into xA
            float2 xf;
            if (L < 128) {
                int bb = L >> 6, i = L & 63;
                xf = *(const float2*)(x + ((size_t)(b0 + bb) * T_STEPS + (t + 1)) * 128 + 2 * i);
            }
#pragma unroll
            for (int bb = 0; bb < 2; ++bb)
                nz[bb] = noise[(((size_t)(b0 + bb) * T_STEPS + (t + 1)) * 2 + 0) * 512 + r];
            if (L < 128) {
                int bb = L >> 6, i = L & 63;
                xA[bb][i >> 4][i & 15] = pack2(xf.x, xf.y);
            }
            __syncthreads();
        }
    } else {
        unsigned wreg[128];
#pragma unroll
        for (int j = 0; j < 128; ++j) {
            wreg[j] = wp1[(wgr * 128 + j) * 256 + L];
            asm volatile("" : "+v"(wreg[j]));
        }
        const float cb = bih1[r] + bhh1[r];

        __shared__ __align__(16) unsigned hA[2][4][68];   // h0(t)
        __shared__ __align__(16) unsigned hB[2][4][68];   // h1(t-1)
        __shared__ float hs[2][512];
        __shared__ float part[2][256];
        for (int i = L; i < 2 * 4 * 68; i += 256) ((unsigned*)hB)[i] = 0u;  // h1(-1)=0
        __syncthreads();
        {   // pre-loop: gather h0(0) (tag 1, slot 0)
            unsigned r0, r1;
            poll2(&h0l[(size_t)b0 * 256 + L], &h0g[(size_t)b0 * 256 + L],
                  &h0l[(size_t)(b0 + 1) * 256 + L], &h0g[(size_t)(b0 + 1) * 256 + L],
                  1u, r0, r1, budget);
            hA[0][L >> 6][L & 63] = r0;
            hA[1][L >> 6][L & 63] = r1;
        }
        __syncthreads();
        float nz[2];
#pragma unroll
        for (int bb = 0; bb < 2; ++bb)
            nz[bb] = noise[(((size_t)(b0 + bb) * T_STEPS) * 2 + 1) * 512 + r];

        for (int t = 0; t < T_STEPS; ++t) {
            // phase-1: h0-part partial (wreg[0..63])
            float p1[2];
#pragma unroll
            for (int bb = 0; bb < 2; ++bb) {
                const uint4* q = (const uint4*)(&hA[bb][c][0]);
                float a0 = 0.f, a1 = 0.f, a2 = 0.f, a3 = 0.f;
#pragma unroll
                for (int jj = 0; jj < 16; ++jj) {
                    uint4 hp = q[jj];
                    a0 = dot2acc(wreg[4 * jj + 0], hp.x, a0);
                    a1 = dot2acc(wreg[4 * jj + 1], hp.y, a1);
                    a2 = dot2acc(wreg[4 * jj + 2], hp.z, a2);
                    a3 = dot2acc(wreg[4 * jj + 3], hp.w, a3);
                }
                p1[bb] = (a0 + a1) + (a2 + a3);
            }
            // poll h1(t-1): tag t, slot (t-1)&3
            if (t > 0) {
                size_t base = (size_t)((t - 1) & (D1RING - 1)) * NBATCH * 256;
                unsigned r0, r1;
                poll2(&h1l[base + (size_t)b0 * 256 + L], &h1g[base + (size_t)b0 * 256 + L],
                      &h1l[base + (size_t)(b0 + 1) * 256 + L], &h1g[base + (size_t)(b0 + 1) * 256 + L],
                      (unsigned)t, r0, r1, budget);
                hB[0][L >> 6][L & 63] = r0;
                hB[1][L >> 6][L & 63] = r1;
            }
            __syncthreads();
            // phase-2: h1-part (wreg[64..127]) — the critical half
            float hnew[2];
#pragma unroll
            for (int bb = 0; bb < 2; ++bb) {
                const uint4* q = (const uint4*)(&hB[bb][c][0]);
                float a0 = 0.f, a1 = 0.f, a2 = 0.f, a3 = 0.f;
#pragma unroll
                for (int jj = 0; jj < 16; ++jj) {
                    uint4 hp = q[jj];
                    a0 = dot2acc(wreg[64 + 4 * jj + 0], hp.x, a0);
                    a1 = dot2acc(wreg[64 + 4 * jj + 1], hp.y, a1);
                    a2 = dot2acc(wreg[64 + 4 * jj + 2], hp.z, a2);
                    a3 = dot2acc(wreg[64 + 4 * jj + 3], hp.w, a3);
                }
                float acc = p1[bb] + (a0 + a1) + (a2 + a3);
                acc += __shfl_xor(acc, 1);
                acc += __shfl_xor(acc, 2);
                hnew[bb] = fast_tanh(acc + cb + nz[bb]);
            }
            // post h1(t): tag t+1, slot t&3
#pragma unroll
            for (int bb = 0; bb < 2; ++bb) {
                float hnb = __shfl_down(hnew[bb], 4);
                if ((L & 7) == 0) {
                    unsigned pv = pack2(hnew[bb], hnb);
                    ull atom = ((ull)(unsigned)(t + 1) << 32) | (ull)pv;
                    size_t idx = ((size_t)(t & (D1RING - 1)) * NBATCH + (b0 + bb)) * 256 + (r >> 1);
                    post_dual(&h1l[idx], &h1g[idx], atom);
                }
            }
            if (t == T_STEPS - 1) break;
            // prefetch nz(t+1)
#pragma unroll
            for (int bb = 0; bb < 2; ++bb)
                nz[bb] = noise[(((size_t)(b0 + bb) * T_STEPS + (t + 1)) * 2 + 1) * 512 + r];
            // gather h0(t+1): tag t+2, slot (t+1)&31
            {
                size_t base = (size_t)((t + 1) & (D0RING - 1)) * NBATCH * 256;
                unsigned r0, r1;
                poll2(&h0l[base + (size_t)b0 * 256 + L], &h0g[base + (size_t)b0 * 256 + L],
                      &h0l[base + (size_t)(b0 + 1) * 256 + L], &h0g[base + (size_t)(b0 + 1) * 256 + L],
                      (unsigned)(t + 2), r0, r1, budget);
                hA[0][L >> 6][L & 63] = r0;
                hA[1][L >> 6][L & 63] = r1;
            }
            __syncthreads();
        }

        // FC epilogue: wgr==0 WGs compute out = h1(T-1) @ fc_w^T + fc_b
        if (wgr == 0) {
            size_t base = (size_t)((T_STEPS - 1) & (D1RING - 1)) * NBATCH * 256;
            unsigned r0, r1;
            poll2(&h1l[base + (size_t)b0 * 256 + L], &h1g[base + (size_t)b0 * 256 + L],
                  &h1l[base + (size_t)(b0 + 1) * 256 + L], &h1g[base + (size_t)(b0 + 1) * 256 + L],
                  (unsigned)T_STEPS, r0, r1, budget);
            half2v h20 = __builtin_bit_cast(half2v, r0);
            half2v h21 = __builtin_bit_cast(half2v, r1);
            hs[0][2 * L] = (float)h20.x; hs[0][2 * L + 1] = (float)h20.y;
            hs[1][2 * L] = (float)h21.x; hs[1][2 * L + 1] = (float)h21.y;
            __syncthreads();
            const int o = L & 31, seg = L >> 5;          // 32 outputs x 8 k-segments
#pragma unroll
            for (int bb = 0; bb < 2; ++bb) {
                const float* wr = fcw + o * 512 + seg * 64;
                const float* hr = &hs[bb][seg * 64];
                float a = 0.f;
#pragma unroll 16
                for (int k = 0; k < 64; ++k) a = fmaf(wr[k], hr[k], a);
                part[bb][L] = a;
            }
            __syncthreads();
            if (L < 64) {
                int bb = L >> 5, oo = L & 31;
                float s = fcb[oo];
#pragma unroll
                for (int sgi = 0; sgi < 8; ++sgi) s += part[bb][sgi * 32 + oo];
                out[(b0 + bb) * 32 + oo] = s;
            }
        }
    }
}

extern "C" void kernel_launch(void* const* d_in, const int* in_sizes, int n_in,
                              void* d_out, int out_size, void* d_ws, size_t ws_size,
                              hipStream_t stream) {
    const float* x     = (const float*)d_in[0];
    const float* noise = (const float*)d_in[1];
    const float* Wih0  = (const float*)d_in[2];
    const float* Wih1  = (const float*)d_in[3];
    const float* Whh0  = (const float*)d_in[4];
    const float* Whh1  = (const float*)d_in[5];
    const float* bih0  = (const float*)d_in[6];
    const float* bih1  = (const float*)d_in[7];
    const float* bhh0  = (const float*)d_in[8];
    const float* bhh1  = (const float*)d_in[9];
    const float* fcw   = (const float*)d_in[10];
    const float* fcb   = (const float*)d_in[11];
    float* out = (float*)d_out;

    char* ws = (char*)d_ws;
    size_t o = 0;
    unsigned* wp0 = (unsigned*)(ws + o); o += (size_t)N0 * 4;           // 640 KB
    unsigned* wp1 = (unsigned*)(ws + o); o += (size_t)N1 * 4;           // 1 MB
    ull* h0l = (ull*)(ws + o); o += (size_t)D0RING * NBATCH * 256 * 8;  // 4 MB
    ull* h0g = (ull*)(ws + o); o += (size_t)D0RING * NBATCH * 256 * 8;  // 4 MB
    ull* h1l = (ull*)(ws + o); o += (size_t)D1RING * NBATCH * 256 * 8;  // 512 KB
    ull* h1g = (ull*)(ws + o); o += (size_t)D1RING * NBATCH * 256 * 8;  // 512 KB

    const int initBlocks = (N0 + N1 + 255) / 256;
    init_pack<<<initBlocks, 256, 0, stream>>>(Wih0, Whh0, Wih1, Whh1, wp0, wp1);
    rnn_dual<<<512, 256, 0, stream>>>(x, noise, wp0, wp1, bih0, bhh0, bih1, bhh1,
                                      fcw, fcb, h0l, h0g, h1l, h1g, out);
}